// Round 5
// baseline (334.800 us; speedup 1.0000x reference)
//
#include <hip/hip_runtime.h>
#include <math.h>

#define HH 224
#define WW 224
#define OH 112
#define OW 112
#define NCH 1024
#define YP 232     // y_s pitch (bf16): 464B rows -> 16B-aligned, ~2-way banks
#define NT 896     // 14 waves
#define SR 32      // strip rows

typedef __attribute__((ext_vector_type(8))) short s16x8;
typedef __attribute__((ext_vector_type(4))) float f32x4;

static __device__ __host__ __forceinline__ unsigned short f2bf(float f) {
    union { float f; unsigned int u; } v; v.f = f;
    unsigned int r = (v.u + 0x7FFFu + ((v.u >> 16) & 1u)) >> 16;  // RNE
    return (unsigned short)r;
}

// Lr bf16 ROW-major [p=112][m=224]
__global__ void lr_init_kernel(unsigned short* __restrict__ lrbf) {
    int idx = blockIdx.x * blockDim.x + threadIdx.x;
    if (idx >= OH * HH) return;
    int p = idx / HH;
    int m = idx % HH;
    float val = 0.0f;
    if ((m & 1) == 0) {
        val = (m == 2 * p) ? 0.5f : 0.0f;
    } else {
        int j = m >> 1;
        int r = 2 * p - m;                       // odd
        float a = (float)M_PI * (float)r * (1.0f / 224.0f);
        float sg = ((p - j) & 1) ? 1.0f : -1.0f; // sigma = -(-1)^(p-j)
        val = sg * (cosf(a) / sinf(a)) * (1.0f / 224.0f);
    }
    lrbf[p * HH + m] = f2bf(val);
}

// 896 threads/block: 14 waves; launchability forces VGPR<=128 -> 3.5 waves/SIMD.
__launch_bounds__(896, 1)
__global__ void flc_mfma_kernel(const float* __restrict__ x,
                                const unsigned short* __restrict__ lrbf,
                                float* __restrict__ out) {
    __shared__ float x_s[2][SR * WW];          // 2 x 28672 B (linear: gload_lds dest)
    __shared__ unsigned short y_s[OH * YP];    // 51968 B
    __shared__ float wsum[14];

    const int c = blockIdx.x;
    const int t = threadIdx.x;
    const int w = t >> 6;       // wave 0..13
    const int l = t & 63;
    const int lr16 = l & 15;
    const int g = l >> 4;       // 0..3

    const float* __restrict__ xc = x + (size_t)c * (HH * WW);

    // ---- prologue: stage strip 0 -> buf 0
    {
        #pragma unroll
        for (int k2 = 0; k2 < 2; ++k2) {
            const float* g2 = xc + (k2 * NT + t) * 4;
            char* lp = (char*)(&x_s[0][0]) + (size_t)(k2 * NT + t) * 16;
            __builtin_amdgcn_global_load_lds(
                (const __attribute__((address_space(1))) unsigned int*)g2,
                (__attribute__((address_space(3))) unsigned int*)lp, 16, 0, 0);
        }
    }
    __syncthreads();   // strip 0 ready

    f32x4 accA[7];
    #pragma unroll
    for (int i = 0; i < 7; ++i) accA[i] = f32x4{0.f, 0.f, 0.f, 0.f};
    float spart = 0.0f;
    const int col = (w << 4) + lr16;   // this wave's n-column, 0..223

    // ---- Phase A: Y = Lr * X, 7 strips of 32; stage(i+1) in flight during compute(i)
    for (int i = 0; i < 7; ++i) {
        const int cur = i & 1;
        const int k0 = i * SR;
        const float* __restrict__ xs = &x_s[cur][0];

        // A-frags first: compiler's pre-MFMA wait is then vmcnt(2),
        // leaving the next-strip gload_lds in flight through compute.
        s16x8 af[7];
        #pragma unroll
        for (int pt = 0; pt < 7; ++pt)
            af[pt] = *(const s16x8*)(lrbf + (pt * 16 + lr16) * HH + k0 + 8 * g);

        // issue next strip -> other buffer (its last reader synced last iter)
        if (i < 6) {
            const float* gp = xc + (k0 + SR) * WW;
            char* xdst = (char*)(&x_s[cur ^ 1][0]);
            #pragma unroll
            for (int k2 = 0; k2 < 2; ++k2) {
                const float* g2 = gp + (k2 * NT + t) * 4;
                char* lp = xdst + (size_t)(k2 * NT + t) * 16;
                __builtin_amdgcn_global_load_lds(
                    (const __attribute__((address_space(1))) unsigned int*)g2,
                    (__attribute__((address_space(3))) unsigned int*)lp, 16, 0, 0);
            }
        }

        // B-frag: column gather fp32 -> bf16
        s16x8 bv;
        #pragma unroll
        for (int j = 0; j < 8; ++j)
            bv[j] = (short)f2bf(xs[(8 * g + j) * WW + col]);
        #pragma unroll
        for (int pt = 0; pt < 7; ++pt)
            accA[pt] = __builtin_amdgcn_mfma_f32_16x16x32_bf16(af[pt], bv, accA[pt], 0, 0, 0);

        // rank-1 partial: s += (-1)^(j+k) X[2j+1][2k+1] over this strip
        #pragma unroll
        for (int rr = 0; rr < 2; ++rr) {
            int e = t + NT * rr;               // 0..1791
            int jj = e / 112, kk = e % 112;
            float v = xs[(2 * jj + 1) * WW + (2 * kk + 1)];
            spart += ((jj + kk) & 1) ? -v : v; // k0/2 even -> no extra sign
        }

        __syncthreads();   // drains next-strip loads exactly when needed; bufs synced
    }

    // wave-reduce spart
    #pragma unroll
    for (int off = 32; off > 0; off >>= 1)
        spart += __shfl_down(spart, off, 64);
    if (l == 0) wsum[w] = spart;

    // write Y tile to LDS as bf16 (D layout: col=lane&15, row=4g+r)
    #pragma unroll
    for (int pt = 0; pt < 7; ++pt) {
        #pragma unroll
        for (int r = 0; r < 4; ++r)
            y_s[(pt * 16 + 4 * g + r) * YP + col] = f2bf(accA[pt][r]);
    }
    __syncthreads();   // y_s + wsum ready

    float ssum = 0.0f;
    #pragma unroll
    for (int w2 = 0; w2 < 14; ++w2) ssum += wsum[w2];
    const float s = ssum * (1.0f / (224.0f * 224.0f));

    // ---- Phase B: Out = Y * Lr^T, 49 16x16 tiles over 14 waves; stores overlap
    float* __restrict__ oc = out + (size_t)c * (OH * OW);
    for (int T = w; T < 49; T += 14) {
        const int pi = T / 7, qi = T % 7;
        f32x4 acc = f32x4{0.f, 0.f, 0.f, 0.f};
        #pragma unroll
        for (int ks = 0; ks < 7; ++ks) {
            s16x8 ya = *(const s16x8*)(&y_s[(pi * 16 + lr16) * YP + ks * 32 + 8 * g]);
            s16x8 bq = *(const s16x8*)(lrbf + (qi * 16 + lr16) * HH + ks * 32 + 8 * g);
            acc = __builtin_amdgcn_mfma_f32_16x16x32_bf16(ya, bq, acc, 0, 0, 0);
        }
        const int q = qi * 16 + lr16;
        #pragma unroll
        for (int r = 0; r < 4; ++r) {
            int p = pi * 16 + 4 * g + r;
            oc[p * OW + q] = acc[r] - (((p + q) & 1) ? -s : s);
        }
    }
}

extern "C" void kernel_launch(void* const* d_in, const int* in_sizes, int n_in,
                              void* d_out, int out_size, void* d_ws, size_t ws_size,
                              hipStream_t stream) {
    const float* x = (const float*)d_in[0];
    float* out = (float*)d_out;
    unsigned short* lrbf = (unsigned short*)d_ws;   // 112*224*2 = 50176 B

    hipLaunchKernelGGL(lr_init_kernel, dim3((OH * HH + 255) / 256), dim3(256), 0, stream, lrbf);
    hipLaunchKernelGGL(flc_mfma_kernel, dim3(NCH), dim3(NT), 0, stream, x, lrbf, out);
}